// Round 4
// baseline (7621.133 us; speedup 1.0000x reference)
//
#include <hip/hip_runtime.h>
#include <math.h>

#define S 2048
#define MARGIN 0.7f
#define ITERS 500
#define NBLK 256    // cooperative grid: 1 block/CU on 256 CUs
#define TPB 512     // 8 waves/block, wave-per-row, 8 rows/block

typedef unsigned long long u64;

// ---------------------------------------------------------------------------
// init: log-marginals, zero accumulators, poison publish tags
// ---------------------------------------------------------------------------
__global__ __launch_bounds__(256) void init_marg_k(const float* __restrict__ qa,
                                                   const float* __restrict__ ta,
                                                   float* __restrict__ lmu,
                                                   float* __restrict__ lnu,
                                                   float* __restrict__ vt,
                                                   float* __restrict__ dist2,
                                                   u64* __restrict__ uPub,
                                                   u64* __restrict__ vPub) {
  int i = blockIdx.x * 256 + threadIdx.x;
  lmu[i] = __logf(qa[i]);
  lnu[i] = __logf(ta[i]);
  vt[i] = 0.f;     // will accumulate y2 (vt init = v0 + y2 = y2 since v0 = 0)
  dist2[i] = 0.f;
  // poison tags (never matches any expected tag 0..ITERS) -> safe across
  // graph replays without any reasoning about stale tag collisions
  const u64 poison = 0xFFFFFFFF00000000ull;
  uPub[i] = poison; uPub[S + i] = poison;
  vPub[i] = poison; vPub[S + i] = poison;
}

// vt[j] += sum_d TF[d,j]^2   (8 j-blocks x 8 d-chunks, atomic combine)
__global__ __launch_bounds__(256) void colsumsq_k(const float* __restrict__ TF,
                                                  float* __restrict__ vt) {
  int jb = blockIdx.x & 7, dc = blockIdx.x >> 3;
  int j = jb * 256 + threadIdx.x;
  int d0 = dc * 256;
  float acc = 0.f;
  for (int d = d0; d < d0 + 256; ++d) {
    float v = TF[d * S + j];
    acc = fmaf(v, v, acc);
  }
  atomicAdd(&vt[j], acc);
}

// vPub slot0 <- pack(vt, tag 0): the initial v-potential for the dataflow loop
__global__ __launch_bounds__(256) void pack_v0_k(const float* __restrict__ vt,
                                                 u64* __restrict__ vPub) {
  int i = blockIdx.x * 256 + threadIdx.x;
  vPub[i] = (u64)__float_as_uint(vt[i]);  // tag 0 in high word
}

// ---------------------------------------------------------------------------
// C[i,j] = alpha * sum_k A[k*S+i] * B[k*S+j]   (128x128 tile, BK=16, 8x8/thread)
// ---------------------------------------------------------------------------
__global__ __launch_bounds__(256) void gemm_tn_k(const float* __restrict__ A,
                                                 const float* __restrict__ B,
                                                 float* __restrict__ C, float alpha) {
  __shared__ float As[16][128];
  __shared__ float Bs[16][128];
  int t = threadIdx.x;
  int i0 = blockIdx.y * 128, j0 = blockIdx.x * 128;
  int tx = t & 15, ty = t >> 4;
  float acc[8][8];
#pragma unroll
  for (int r = 0; r < 8; ++r)
#pragma unroll
    for (int c = 0; c < 8; ++c) acc[r][c] = 0.f;

  int e = t * 4;
  int dd0 = e >> 7, ii = e & 127;
  int dd1 = dd0 + 8;
  for (int k0 = 0; k0 < S; k0 += 16) {
    float4 a0 = *(const float4*)&A[(k0 + dd0) * S + i0 + ii];
    float4 b0 = *(const float4*)&B[(k0 + dd0) * S + j0 + ii];
    float4 a1 = *(const float4*)&A[(k0 + dd1) * S + i0 + ii];
    float4 b1 = *(const float4*)&B[(k0 + dd1) * S + j0 + ii];
    __syncthreads();
    *(float4*)&As[dd0][ii] = a0; *(float4*)&Bs[dd0][ii] = b0;
    *(float4*)&As[dd1][ii] = a1; *(float4*)&Bs[dd1][ii] = b1;
    __syncthreads();
#pragma unroll
    for (int kk = 0; kk < 16; ++kk) {
      float a[8], b[8];
      *(float4*)&a[0] = *(const float4*)&As[kk][ty * 8];
      *(float4*)&a[4] = *(const float4*)&As[kk][ty * 8 + 4];
      *(float4*)&b[0] = *(const float4*)&Bs[kk][tx * 4];
      *(float4*)&b[4] = *(const float4*)&Bs[kk][64 + tx * 4];
#pragma unroll
      for (int r = 0; r < 8; ++r)
#pragma unroll
        for (int c = 0; c < 8; ++c) acc[r][c] = fmaf(a[r], b[c], acc[r][c]);
    }
  }
#pragma unroll
  for (int r = 0; r < 8; ++r) {
    int i = i0 + ty * 8 + r;
    float4 o0 = make_float4(acc[r][0] * alpha, acc[r][1] * alpha, acc[r][2] * alpha, acc[r][3] * alpha);
    float4 o1 = make_float4(acc[r][4] * alpha, acc[r][5] * alpha, acc[r][6] * alpha, acc[r][7] * alpha);
    *(float4*)&C[i * S + j0 + tx * 4] = o0;
    *(float4*)&C[i * S + j0 + 64 + tx * 4] = o1;
  }
}

// ---------------------------------------------------------------------------
// out[j*S+i] = in[i*S+j]  (64x64 LDS tiles)
// ---------------------------------------------------------------------------
__global__ __launch_bounds__(256) void transpose_k(const float* __restrict__ in,
                                                   float* __restrict__ out) {
  __shared__ float tile[64][65];
  int i0 = blockIdx.y * 64, j0 = blockIdx.x * 64;
  int tx = threadIdx.x & 63, ty = threadIdx.x >> 6;  // ty 0..3
#pragma unroll
  for (int r = 0; r < 16; ++r) {
    int row = r * 4 + ty;
    tile[row][tx] = in[(i0 + row) * S + j0 + tx];
  }
  __syncthreads();
#pragma unroll
  for (int r = 0; r < 16; ++r) {
    int row = r * 4 + ty;
    out[(j0 + row) * S + i0 + tx] = tile[tx][row];
  }
}

// ---------------------------------------------------------------------------
// Persistent cooperative Sinkhorn — LDS-resident G + DATAFLOW sync (no barrier).
//
// 256 blocks x 512 threads, 1 block/CU (forced by 144KB static LDS). Each
// block stages its 8 Gp + 8 GpT rows into LDS once. Per half-iteration, the
// 2048 new potential values are published as (tag<<32 | value_bits) in ONE
// naturally-atomic 8B relaxed agent-scope store each; consumers poll their
// own 4 entries until tags match. Payload and flag share the word -> no
// fences, no grid barrier, no two-level counters (round 3's ~2us/phase
// barrier leg deleted). Max inter-block skew is self-limited to 1 phase by
// the data dependency, so phases pipeline instead of synchronizing.
// Double-buffered slots (it&1) are WAR-safe: overwriting v_t requires all
// u_{t+2} published => all blocks read v_{t+1} => all blocks published
// u_{t+1} => all blocks fully read v_t. Cross-replay staleness killed by
// tag poisoning in init. Arithmetic bit-identical to the verified round 3.
// ---------------------------------------------------------------------------
#define PADD(P, A) P.x += A.x; P.y += A.y; P.z += A.z; P.w += A.w
#define PMAX(P) fmaxf(fmaxf(P.x, P.y), fmaxf(P.z, P.w))
#define PEXPS(P) (__expf(P.x - m) + __expf(P.y - m) + __expf(P.z - m) + __expf(P.w - m))

// poll own 4 contiguous entries of pub until tag matches; deposit into s_pot
__device__ __forceinline__ void stage_pub(const u64* __restrict__ pub,
                                          float* __restrict__ s_pot,
                                          int t, unsigned tag) {
  int e0 = t << 2;
  // first round: issue all 4 loads back-to-back for MLP
  u64 w0 = __hip_atomic_load(&pub[e0 + 0], __ATOMIC_RELAXED, __HIP_MEMORY_SCOPE_AGENT);
  u64 w1 = __hip_atomic_load(&pub[e0 + 1], __ATOMIC_RELAXED, __HIP_MEMORY_SCOPE_AGENT);
  u64 w2 = __hip_atomic_load(&pub[e0 + 2], __ATOMIC_RELAXED, __HIP_MEMORY_SCOPE_AGENT);
  u64 w3 = __hip_atomic_load(&pub[e0 + 3], __ATOMIC_RELAXED, __HIP_MEMORY_SCOPE_AGENT);
  unsigned got = 0;
  if ((unsigned)(w0 >> 32) == tag) { s_pot[e0 + 0] = __uint_as_float((unsigned)w0); got |= 1u; }
  if ((unsigned)(w1 >> 32) == tag) { s_pot[e0 + 1] = __uint_as_float((unsigned)w1); got |= 2u; }
  if ((unsigned)(w2 >> 32) == tag) { s_pot[e0 + 2] = __uint_as_float((unsigned)w2); got |= 4u; }
  if ((unsigned)(w3 >> 32) == tag) { s_pot[e0 + 3] = __uint_as_float((unsigned)w3); got |= 8u; }
  while (got != 0xFu) {
    __builtin_amdgcn_s_sleep(2);
#pragma unroll
    for (int k = 0; k < 4; ++k) {
      if (!(got & (1u << k))) {
        u64 w = __hip_atomic_load(&pub[e0 + k], __ATOMIC_RELAXED, __HIP_MEMORY_SCOPE_AGENT);
        if ((unsigned)(w >> 32) == tag) {
          s_pot[e0 + k] = __uint_as_float((unsigned)w);
          got |= 1u << k;
        }
      }
    }
  }
  __syncthreads();  // s_pot fully populated for all waves
}

// wave-uniform LSE over 2048 entries of (grow[j] + s_pot[j]); exact row max
__device__ __forceinline__ float lse_row(const float* __restrict__ grow,
                                         const float* __restrict__ s_pot,
                                         int lane) {
  int j0 = lane << 2;
  float4 p0 = *(const float4*)&s_pot[j0];
  float4 p1 = *(const float4*)&s_pot[j0 + 256];
  float4 p2 = *(const float4*)&s_pot[j0 + 512];
  float4 p3 = *(const float4*)&s_pot[j0 + 768];
  float4 p4 = *(const float4*)&s_pot[j0 + 1024];
  float4 p5 = *(const float4*)&s_pot[j0 + 1280];
  float4 p6 = *(const float4*)&s_pot[j0 + 1536];
  float4 p7 = *(const float4*)&s_pot[j0 + 1792];
  float4 a0 = *(const float4*)&grow[j0];
  float4 a1 = *(const float4*)&grow[j0 + 256];
  float4 a2 = *(const float4*)&grow[j0 + 512];
  float4 a3 = *(const float4*)&grow[j0 + 768];
  float4 a4 = *(const float4*)&grow[j0 + 1024];
  float4 a5 = *(const float4*)&grow[j0 + 1280];
  float4 a6 = *(const float4*)&grow[j0 + 1536];
  float4 a7 = *(const float4*)&grow[j0 + 1792];
  PADD(p0, a0); PADD(p1, a1); PADD(p2, a2); PADD(p3, a3);
  PADD(p4, a4); PADD(p5, a5); PADD(p6, a6); PADD(p7, a7);
  float m0 = PMAX(p0), m1 = PMAX(p1), m2 = PMAX(p2), m3 = PMAX(p3);
  float m4 = PMAX(p4), m5 = PMAX(p5), m6 = PMAX(p6), m7 = PMAX(p7);
  m0 = fmaxf(m0, m1); m2 = fmaxf(m2, m3); m4 = fmaxf(m4, m5); m6 = fmaxf(m6, m7);
  float m = fmaxf(fmaxf(m0, m2), fmaxf(m4, m6));
#pragma unroll
  for (int off = 32; off; off >>= 1) m = fmaxf(m, __shfl_xor(m, off));
  float s = PEXPS(p0) + PEXPS(p1) + PEXPS(p2) + PEXPS(p3) +
            PEXPS(p4) + PEXPS(p5) + PEXPS(p6) + PEXPS(p7);
#pragma unroll
  for (int off = 32; off; off >>= 1) s += __shfl_xor(s, off);
  return m + __logf(s);
}

__global__ __launch_bounds__(TPB) void sinkhorn_k(
    const float* __restrict__ Gp, const float* __restrict__ GpT,
    const float* __restrict__ lmu, const float* __restrict__ lnu,
    float* __restrict__ ut, float* __restrict__ vt,
    u64* __restrict__ uPub, u64* __restrict__ vPub) {
  __shared__ float s_gu[8 * S];    // 64KB: this block's 8 Gp rows
  __shared__ float s_gv[8 * S];    // 64KB: this block's 8 GpT rows
  __shared__ float s_potA[S];      // 8KB : staged v for u-pass
  __shared__ float s_potB[S];      // 8KB : staged u for v-pass

  const int t = threadIdx.x;
  const int wv = t >> 6, lane = t & 63;
  const int row = ((int)blockIdx.x << 3) + wv;

  // one-time stage of this block's G rows into LDS
  {
    const float* gu = Gp + (size_t)row * S;
    const float* gv = GpT + (size_t)row * S;
    float* lgu = s_gu + wv * S;
    float* lgv = s_gv + wv * S;
#pragma unroll
    for (int c = 0; c < 8; ++c) {
      int j = (lane << 2) + (c << 8);
      *(float4*)&lgu[j] = *(const float4*)&gu[j];
      *(float4*)&lgv[j] = *(const float4*)&gv[j];
    }
  }
  const float lmu_r = lmu[row];
  const float lnu_r = lnu[row];
  const float* grow_u = s_gu + wv * S;
  const float* grow_v = s_gv + wv * S;
  float uLast = 0.f, vLast = 0.f;
  __syncthreads();

  for (int it = 0; it < ITERS; ++it) {
    const int slot = (it & 1) << 11;  // *S

    // ---- u-pass: u_it[row] = lmu - LSE_j(Gp[row,j] + v_it[j]) ----
    stage_pub(vPub + slot, s_potA, t, (unsigned)it);
    {
      float nv = lmu_r - lse_row(grow_u, s_potA, lane);
      uLast = nv;
      if (lane == 0)
        __hip_atomic_store(&uPub[slot + row],
                           ((u64)(unsigned)it << 32) | (u64)__float_as_uint(nv),
                           __ATOMIC_RELAXED, __HIP_MEMORY_SCOPE_AGENT);
    }
    // ---- v-pass: v_{it+1}[row] = lnu - LSE_i(GpT[row,i] + u_it[i]) ----
    // stage_pub's internal __syncthreads also separates all reads of s_potA
    // (lse_row above) from next iteration's writes to it.
    stage_pub(uPub + slot, s_potB, t, (unsigned)it);
    {
      float nv = lnu_r - lse_row(grow_v, s_potB, lane);
      vLast = nv;
      if (lane == 0)
        __hip_atomic_store(&vPub[(slot ^ 2048) + row],
                           ((u64)(unsigned)(it + 1) << 32) | (u64)__float_as_uint(nv),
                           __ATOMIC_RELAXED, __HIP_MEMORY_SCOPE_AGENT);
    }
  }
  // final potentials -> plain arrays for the epilogue kernels
  // (kernel-boundary release/acquire handles cross-XCD visibility)
  if (lane == 0) {
    ut[row] = uLast;
    vt[row] = vLast;
  }
}

// ---------------------------------------------------------------------------
// RT[d,i] = sum_j TF[d,j] * exp( GpT[j*S+i] + ut[i] + vt[j] )
// ---------------------------------------------------------------------------
__global__ __launch_bounds__(256) void rt_gemm_k(const float* __restrict__ TF,
                                                 const float* __restrict__ GpT,
                                                 const float* __restrict__ ut,
                                                 const float* __restrict__ vt,
                                                 float* __restrict__ RT) {
  __shared__ float As[16][128];
  __shared__ float Bs[16][128];
  int t = threadIdx.x;
  int d0 = blockIdx.y * 128, i0 = blockIdx.x * 128;
  int tx = t & 15, ty = t >> 4;
  float acc[8][8];
#pragma unroll
  for (int r = 0; r < 8; ++r)
#pragma unroll
    for (int c = 0; c < 8; ++c) acc[r][c] = 0.f;

  int akk = (t * 4) & 15, add0 = t >> 2;
  int eb = t * 4;
  int bkk0 = eb >> 7, bii = eb & 127, bkk1 = bkk0 + 8;
  float4 u4 = *(const float4*)&ut[i0 + bii];

  for (int k0 = 0; k0 < S; k0 += 16) {
    float4 av0 = *(const float4*)&TF[(d0 + add0) * S + k0 + akk];
    float4 av1 = *(const float4*)&TF[(d0 + add0 + 64) * S + k0 + akk];
    float4 g0 = *(const float4*)&GpT[(k0 + bkk0) * S + i0 + bii];
    float4 g1 = *(const float4*)&GpT[(k0 + bkk1) * S + i0 + bii];
    float v0 = vt[k0 + bkk0], v1 = vt[k0 + bkk1];
    __syncthreads();
    As[akk + 0][add0] = av0.x; As[akk + 1][add0] = av0.y;
    As[akk + 2][add0] = av0.z; As[akk + 3][add0] = av0.w;
    As[akk + 0][add0 + 64] = av1.x; As[akk + 1][add0 + 64] = av1.y;
    As[akk + 2][add0 + 64] = av1.z; As[akk + 3][add0 + 64] = av1.w;
    float4 p0 = make_float4(__expf(g0.x + u4.x + v0), __expf(g0.y + u4.y + v0),
                            __expf(g0.z + u4.z + v0), __expf(g0.w + u4.w + v0));
    float4 p1 = make_float4(__expf(g1.x + u4.x + v1), __expf(g1.y + u4.y + v1),
                            __expf(g1.z + u4.z + v1), __expf(g1.w + u4.w + v1));
    *(float4*)&Bs[bkk0][bii] = p0;
    *(float4*)&Bs[bkk1][bii] = p1;
    __syncthreads();
#pragma unroll
    for (int kk = 0; kk < 16; ++kk) {
      float a[8], b[8];
      *(float4*)&a[0] = *(const float4*)&As[kk][ty * 8];
      *(float4*)&a[4] = *(const float4*)&As[kk][ty * 8 + 4];
      *(float4*)&b[0] = *(const float4*)&Bs[kk][tx * 4];
      *(float4*)&b[4] = *(const float4*)&Bs[kk][64 + tx * 4];
#pragma unroll
      for (int r = 0; r < 8; ++r)
#pragma unroll
        for (int c = 0; c < 8; ++c) acc[r][c] = fmaf(a[r], b[c], acc[r][c]);
    }
  }
#pragma unroll
  for (int r = 0; r < 8; ++r) {
    int d = d0 + ty * 8 + r;
    *(float4*)&RT[d * S + i0 + tx * 4] = *(float4*)&acc[r][0];
    *(float4*)&RT[d * S + i0 + 64 + tx * 4] = *(float4*)&acc[r][4];
  }
}

// dist2[i] += sum_{d in chunk} (qa[i]*QF[d,i] - RT[d,i])^2
__global__ __launch_bounds__(256) void dist2_partial_k(const float* __restrict__ QF,
                                                       const float* __restrict__ RT,
                                                       const float* __restrict__ qa,
                                                       float* __restrict__ dist2) {
  int ib = blockIdx.x & 7, dc = blockIdx.x >> 3;
  int i = ib * 256 + threadIdx.x;
  float qai = qa[i];
  float acc = 0.f;
  int d0 = dc * 256;
  for (int d = d0; d < d0 + 256; ++d) {
    float q = QF[d * S + i];
    float r = RT[d * S + i];
    float x = fmaf(qai, q, -r);
    acc = fmaf(x, x, acc);
  }
  atomicAdd(&dist2[i], acc);
}

__global__ __launch_bounds__(256) void loss_final_k(const float* __restrict__ dist2,
                                                    const float* __restrict__ label,
                                                    float* __restrict__ out) {
  int t = threadIdx.x;
  float acc = 0.f;
#pragma unroll
  for (int k = 0; k < 8; ++k) {
    int i = t + k * 256;
    float d2 = dist2[i];
    float dist = sqrtf(d2);
    float lab = label[i];
    float neg = fmaxf(MARGIN - dist, 0.f);
    acc += 0.5f * lab * d2 + 0.5f * (1.f - lab) * neg * neg;
  }
#pragma unroll
  for (int off = 32; off; off >>= 1) acc += __shfl_xor(acc, off);
  __shared__ float wsum[4];
  int wave = t >> 6, lane = t & 63;
  if (lane == 0) wsum[wave] = acc;
  __syncthreads();
  if (t == 0) out[0] = wsum[0] + wsum[1] + wsum[2] + wsum[3];
}

// ---------------------------------------------------------------------------
extern "C" void kernel_launch(void* const* d_in, const int* in_sizes, int n_in,
                              void* d_out, int out_size, void* d_ws, size_t ws_size,
                              hipStream_t stream) {
  const float* QF  = (const float*)d_in[0];  // [D, m] d-major
  const float* qa  = (const float*)d_in[1];  // [m]
  const float* TF  = (const float*)d_in[2];  // [D, n] d-major
  const float* ta  = (const float*)d_in[3];  // [n]
  const float* lab = (const float*)d_in[4];  // [m]
  float* out = (float*)d_out;

  float* ws = (float*)d_ws;
  float* Gp    = ws;                  // S*S : G' = -2 X^T Y  (reused as RT later)
  float* GpT   = Gp + S * S;          // S*S : G'^T
  float* ut    = GpT + S * S;         // S
  float* vt    = ut + S;              // S
  float* lmu   = vt + S;              // S
  float* lnu   = lmu + S;             // S
  float* dist2 = lnu + S;             // S
  u64* uPub = (u64*)(dist2 + S);      // [2][S] u64 : tagged u potentials
  u64* vPub = uPub + 2 * S;           // [2][S] u64 : tagged v potentials
  // total: 2*S*S + 5*S floats + 4*S u64 ~= 33.7 MB

  init_marg_k<<<8, 256, 0, stream>>>(qa, ta, lmu, lnu, vt, dist2, uPub, vPub);
  colsumsq_k<<<64, 256, 0, stream>>>(TF, vt);  // vt = y2 (== v0 + y2)
  pack_v0_k<<<8, 256, 0, stream>>>(vt, vPub);  // vPub slot0 <- (y2, tag 0)
  gemm_tn_k<<<dim3(16, 16), 256, 0, stream>>>(QF, TF, Gp, -2.0f);
  transpose_k<<<dim3(32, 32), 256, 0, stream>>>(Gp, GpT);

  // whole Sinkhorn loop in one persistent cooperative kernel (144KB LDS)
  {
    const float* cGp = Gp; const float* cGpT = GpT;
    const float* clmu = lmu; const float* clnu = lnu;
    float* cut = ut; float* cvt = vt;
    u64* cuPub = uPub; u64* cvPub = vPub;
    void* kargs[] = {&cGp, &cGpT, &clmu, &clnu, &cut, &cvt, &cuPub, &cvPub};
    hipLaunchCooperativeKernel((const void*)sinkhorn_k, dim3(NBLK), dim3(TPB),
                               kargs, 0, stream);
  }

  // RT = P @ tf computed transposed: RT[d,i]; aliases Gp (G' dead after loop)
  rt_gemm_k<<<dim3(16, 16), 256, 0, stream>>>(TF, GpT, ut, vt, Gp);
  dist2_partial_k<<<64, 256, 0, stream>>>(QF, Gp, qa, dist2);
  loss_final_k<<<1, 256, 0, stream>>>(dist2, lab, out);
}

// Round 5
// 5749.845 us; speedup vs baseline: 1.3255x; 1.3255x over previous
//
#include <hip/hip_runtime.h>
#include <math.h>

#define S 2048
#define MARGIN 0.7f
#define ITERS 500
#define NBLK 256    // cooperative grid: 1 block/CU on 256 CUs
#define TPB 512     // 8 waves/block, wave-per-row, 8 rows/block

typedef unsigned long long u64;

// ---------------------------------------------------------------------------
// init: log-marginals, zero accumulators, poison readiness flags
// ---------------------------------------------------------------------------
__global__ __launch_bounds__(256) void init_marg_k(const float* __restrict__ qa,
                                                   const float* __restrict__ ta,
                                                   float* __restrict__ lmu,
                                                   float* __restrict__ lnu,
                                                   float* __restrict__ vt,
                                                   float* __restrict__ dist2,
                                                   unsigned* __restrict__ flagU,
                                                   unsigned* __restrict__ flagV) {
  int i = blockIdx.x * 256 + threadIdx.x;
  lmu[i] = __logf(qa[i]);
  lnu[i] = __logf(ta[i]);
  vt[i] = 0.f;     // will accumulate y2 (vt init = v0 + y2 = y2 since v0 = 0)
  dist2[i] = 0.f;
  // poison (never equals any tag 0..ITERS) -> safe across graph replays
  if (i < 512) { flagU[i] = 0xFFFFFFFFu; flagV[i] = 0xFFFFFFFFu; }
}

// vt[j] += sum_d TF[d,j]^2   (8 j-blocks x 8 d-chunks, atomic combine)
__global__ __launch_bounds__(256) void colsumsq_k(const float* __restrict__ TF,
                                                  float* __restrict__ vt) {
  int jb = blockIdx.x & 7, dc = blockIdx.x >> 3;
  int j = jb * 256 + threadIdx.x;
  int d0 = dc * 256;
  float acc = 0.f;
  for (int d = d0; d < d0 + 256; ++d) {
    float v = TF[d * S + j];
    acc = fmaf(v, v, acc);
  }
  atomicAdd(&vt[j], acc);
}

// valV slot0 <- vt (v_0 + y2), flagV slot0 <- tag 0
__global__ __launch_bounds__(256) void pack_v0_k(const float* __restrict__ vt,
                                                 float* __restrict__ valV,
                                                 unsigned* __restrict__ flagV) {
  int i = blockIdx.x * 256 + threadIdx.x;
  valV[i] = vt[i];
  if (i < 256) flagV[i] = 0u;
}

// ---------------------------------------------------------------------------
// C[i,j] = alpha * sum_k A[k*S+i] * B[k*S+j]   (128x128 tile, BK=16, 8x8/thread)
// ---------------------------------------------------------------------------
__global__ __launch_bounds__(256) void gemm_tn_k(const float* __restrict__ A,
                                                 const float* __restrict__ B,
                                                 float* __restrict__ C, float alpha) {
  __shared__ float As[16][128];
  __shared__ float Bs[16][128];
  int t = threadIdx.x;
  int i0 = blockIdx.y * 128, j0 = blockIdx.x * 128;
  int tx = t & 15, ty = t >> 4;
  float acc[8][8];
#pragma unroll
  for (int r = 0; r < 8; ++r)
#pragma unroll
    for (int c = 0; c < 8; ++c) acc[r][c] = 0.f;

  int e = t * 4;
  int dd0 = e >> 7, ii = e & 127;
  int dd1 = dd0 + 8;
  for (int k0 = 0; k0 < S; k0 += 16) {
    float4 a0 = *(const float4*)&A[(k0 + dd0) * S + i0 + ii];
    float4 b0 = *(const float4*)&B[(k0 + dd0) * S + j0 + ii];
    float4 a1 = *(const float4*)&A[(k0 + dd1) * S + i0 + ii];
    float4 b1 = *(const float4*)&B[(k0 + dd1) * S + j0 + ii];
    __syncthreads();
    *(float4*)&As[dd0][ii] = a0; *(float4*)&Bs[dd0][ii] = b0;
    *(float4*)&As[dd1][ii] = a1; *(float4*)&Bs[dd1][ii] = b1;
    __syncthreads();
#pragma unroll
    for (int kk = 0; kk < 16; ++kk) {
      float a[8], b[8];
      *(float4*)&a[0] = *(const float4*)&As[kk][ty * 8];
      *(float4*)&a[4] = *(const float4*)&As[kk][ty * 8 + 4];
      *(float4*)&b[0] = *(const float4*)&Bs[kk][tx * 4];
      *(float4*)&b[4] = *(const float4*)&Bs[kk][64 + tx * 4];
#pragma unroll
      for (int r = 0; r < 8; ++r)
#pragma unroll
        for (int c = 0; c < 8; ++c) acc[r][c] = fmaf(a[r], b[c], acc[r][c]);
    }
  }
#pragma unroll
  for (int r = 0; r < 8; ++r) {
    int i = i0 + ty * 8 + r;
    float4 o0 = make_float4(acc[r][0] * alpha, acc[r][1] * alpha, acc[r][2] * alpha, acc[r][3] * alpha);
    float4 o1 = make_float4(acc[r][4] * alpha, acc[r][5] * alpha, acc[r][6] * alpha, acc[r][7] * alpha);
    *(float4*)&C[i * S + j0 + tx * 4] = o0;
    *(float4*)&C[i * S + j0 + 64 + tx * 4] = o1;
  }
}

// ---------------------------------------------------------------------------
// out[j*S+i] = in[i*S+j]  (64x64 LDS tiles)
// ---------------------------------------------------------------------------
__global__ __launch_bounds__(256) void transpose_k(const float* __restrict__ in,
                                                   float* __restrict__ out) {
  __shared__ float tile[64][65];
  int i0 = blockIdx.y * 64, j0 = blockIdx.x * 64;
  int tx = threadIdx.x & 63, ty = threadIdx.x >> 6;  // ty 0..3
#pragma unroll
  for (int r = 0; r < 16; ++r) {
    int row = r * 4 + ty;
    tile[row][tx] = in[(i0 + row) * S + j0 + tx];
  }
  __syncthreads();
#pragma unroll
  for (int r = 0; r < 16; ++r) {
    int row = r * 4 + ty;
    out[(j0 + row) * S + i0 + tx] = tile[tx][row];
  }
}

// ---------------------------------------------------------------------------
// Persistent cooperative Sinkhorn — LDS-resident G + per-block flag dataflow.
//
// 256 blocks x 512 threads, 1 block/CU (144KB static LDS). Per phase:
//   producer: 8 lane0s store float values (relaxed agent) -> __syncthreads
//             (compiler drains vmcnt(0): values at coherence point) -> t0
//             stores one tagged per-block flag (relaxed agent).
//   consumer: WAVE 0 ONLY polls the 256 flags (64 lanes x 4, got-mask,
//             s_sleep(1); 1KB/block/round) -> __syncthreads -> all 512
//             threads bulk-load the 8KB value vector (stride-1 u64 agent
//             loads) -> LDS u64 deposit (2-way bank alias = free).
// vs round 3: deletes the grp->gbar two-level RMW chain (~1.4us/phase).
// vs round 4: 64 pollers not 131072, 1KB poll state not 16KB, no scalar
// stride-4 LDS deposits (7.6e7 bank-conflict cycles -> ~0).
// WAR safety (slot = it&1): block b overwrites slot data for phase p+2 only
// after polling ALL blocks' phase-p+1 flags, which requires every block to
// have fully consumed phase p. Tags strictly increase; flags poisoned in
// init for graph-replay safety. Arithmetic bit-identical to rounds 0/3/4.
// ---------------------------------------------------------------------------
#define PADD(P, A) P.x += A.x; P.y += A.y; P.z += A.z; P.w += A.w
#define PMAX(P) fmaxf(fmaxf(P.x, P.y), fmaxf(P.z, P.w))
#define PEXPS(P) (__expf(P.x - m) + __expf(P.y - m) + __expf(P.z - m) + __expf(P.w - m))

// wave 0 polls 256 per-block flags for == tag
__device__ __forceinline__ void poll_flags(const unsigned* __restrict__ f,
                                           int t, unsigned tag) {
  if (t < 64) {
    int e0 = t << 2;
    unsigned got = 0;
    for (;;) {
#pragma unroll
      for (int k = 0; k < 4; ++k)
        if (!(got & (1u << k)))
          if (__hip_atomic_load(&f[e0 + k], __ATOMIC_RELAXED,
                                __HIP_MEMORY_SCOPE_AGENT) == tag)
            got |= 1u << k;
      if (got == 0xFu) break;
      __builtin_amdgcn_s_sleep(1);
    }
  }
  __syncthreads();
}

// all 512 threads: 8KB value vector -> LDS (stride-1 u64, conflict-free)
__device__ __forceinline__ void stage_val(const float* __restrict__ val,
                                          float* __restrict__ s_pot, int t) {
  const u64* src = (const u64*)val;
  u64 w0 = __hip_atomic_load(&src[t], __ATOMIC_RELAXED, __HIP_MEMORY_SCOPE_AGENT);
  u64 w1 = __hip_atomic_load(&src[t + 512], __ATOMIC_RELAXED, __HIP_MEMORY_SCOPE_AGENT);
  ((u64*)s_pot)[t] = w0;
  ((u64*)s_pot)[t + 512] = w1;
  __syncthreads();
}

// wave-uniform LSE over 2048 entries of (grow[j] + s_pot[j]); exact row max
__device__ __forceinline__ float lse_row(const float* __restrict__ grow,
                                         const float* __restrict__ s_pot,
                                         int lane) {
  int j0 = lane << 2;
  float4 p0 = *(const float4*)&s_pot[j0];
  float4 p1 = *(const float4*)&s_pot[j0 + 256];
  float4 p2 = *(const float4*)&s_pot[j0 + 512];
  float4 p3 = *(const float4*)&s_pot[j0 + 768];
  float4 p4 = *(const float4*)&s_pot[j0 + 1024];
  float4 p5 = *(const float4*)&s_pot[j0 + 1280];
  float4 p6 = *(const float4*)&s_pot[j0 + 1536];
  float4 p7 = *(const float4*)&s_pot[j0 + 1792];
  float4 a0 = *(const float4*)&grow[j0];
  float4 a1 = *(const float4*)&grow[j0 + 256];
  float4 a2 = *(const float4*)&grow[j0 + 512];
  float4 a3 = *(const float4*)&grow[j0 + 768];
  float4 a4 = *(const float4*)&grow[j0 + 1024];
  float4 a5 = *(const float4*)&grow[j0 + 1280];
  float4 a6 = *(const float4*)&grow[j0 + 1536];
  float4 a7 = *(const float4*)&grow[j0 + 1792];
  PADD(p0, a0); PADD(p1, a1); PADD(p2, a2); PADD(p3, a3);
  PADD(p4, a4); PADD(p5, a5); PADD(p6, a6); PADD(p7, a7);
  float m0 = PMAX(p0), m1 = PMAX(p1), m2 = PMAX(p2), m3 = PMAX(p3);
  float m4 = PMAX(p4), m5 = PMAX(p5), m6 = PMAX(p6), m7 = PMAX(p7);
  m0 = fmaxf(m0, m1); m2 = fmaxf(m2, m3); m4 = fmaxf(m4, m5); m6 = fmaxf(m6, m7);
  float m = fmaxf(fmaxf(m0, m2), fmaxf(m4, m6));
#pragma unroll
  for (int off = 32; off; off >>= 1) m = fmaxf(m, __shfl_xor(m, off));
  float s = PEXPS(p0) + PEXPS(p1) + PEXPS(p2) + PEXPS(p3) +
            PEXPS(p4) + PEXPS(p5) + PEXPS(p6) + PEXPS(p7);
#pragma unroll
  for (int off = 32; off; off >>= 1) s += __shfl_xor(s, off);
  return m + __logf(s);
}

__global__ __launch_bounds__(TPB) void sinkhorn_k(
    const float* __restrict__ Gp, const float* __restrict__ GpT,
    const float* __restrict__ lmu, const float* __restrict__ lnu,
    float* __restrict__ ut, float* __restrict__ vt,
    float* __restrict__ valU, float* __restrict__ valV,
    unsigned* __restrict__ flagU, unsigned* __restrict__ flagV) {
  __shared__ float s_gu[8 * S];    // 64KB: this block's 8 Gp rows
  __shared__ float s_gv[8 * S];    // 64KB: this block's 8 GpT rows
  __shared__ float s_potA[S];      // 8KB : staged v for u-pass
  __shared__ float s_potB[S];      // 8KB : staged u for v-pass

  const int t = threadIdx.x;
  const int wv = t >> 6, lane = t & 63;
  const int bid = (int)blockIdx.x;
  const int row = (bid << 3) + wv;

  // one-time stage of this block's G rows into LDS
  {
    const float* gu = Gp + (size_t)row * S;
    const float* gv = GpT + (size_t)row * S;
    float* lgu = s_gu + wv * S;
    float* lgv = s_gv + wv * S;
#pragma unroll
    for (int c = 0; c < 8; ++c) {
      int j = (lane << 2) + (c << 8);
      *(float4*)&lgu[j] = *(const float4*)&gu[j];
      *(float4*)&lgv[j] = *(const float4*)&gv[j];
    }
  }
  const float lmu_r = lmu[row];
  const float lnu_r = lnu[row];
  const float* grow_u = s_gu + wv * S;
  const float* grow_v = s_gv + wv * S;
  float uLast = 0.f, vLast = 0.f;
  __syncthreads();

  for (int it = 0; it < ITERS; ++it) {
    const int slot = it & 1;
    const unsigned tag = (unsigned)it;

    // ---- u-pass: u_it[row] = lmu - LSE_j(Gp[row,j] + v_it[j]) ----
    poll_flags(flagV + (slot << 8), t, tag);
    stage_val(valV + (slot << 11), s_potA, t);
    {
      float nv = lmu_r - lse_row(grow_u, s_potA, lane);
      uLast = nv;
      if (lane == 0)
        __hip_atomic_store(&valU[(slot << 11) + row], nv,
                           __ATOMIC_RELAXED, __HIP_MEMORY_SCOPE_AGENT);
    }
    __syncthreads();  // drains value stores (vmcnt(0) before s_barrier)
    if (t == 0)
      __hip_atomic_store(&flagU[(slot << 8) + bid], tag,
                         __ATOMIC_RELAXED, __HIP_MEMORY_SCOPE_AGENT);

    // ---- v-pass: v_{it+1}[row] = lnu - LSE_i(GpT[row,i] + u_it[i]) ----
    poll_flags(flagU + (slot << 8), t, tag);
    stage_val(valU + (slot << 11), s_potB, t);
    {
      float nv = lnu_r - lse_row(grow_v, s_potB, lane);
      vLast = nv;
      if (lane == 0)
        __hip_atomic_store(&valV[((slot ^ 1) << 11) + row], nv,
                           __ATOMIC_RELAXED, __HIP_MEMORY_SCOPE_AGENT);
    }
    __syncthreads();
    if (t == 0)
      __hip_atomic_store(&flagV[((slot ^ 1) << 8) + bid], tag + 1u,
                         __ATOMIC_RELAXED, __HIP_MEMORY_SCOPE_AGENT);
  }
  // final potentials -> plain arrays for the epilogue kernels
  // (end-of-kernel L2 writeback handles cross-kernel visibility)
  if (lane == 0) {
    ut[row] = uLast;
    vt[row] = vLast;
  }
}

// ---------------------------------------------------------------------------
// RT[d,i] = sum_j TF[d,j] * exp( GpT[j*S+i] + ut[i] + vt[j] )
// ---------------------------------------------------------------------------
__global__ __launch_bounds__(256) void rt_gemm_k(const float* __restrict__ TF,
                                                 const float* __restrict__ GpT,
                                                 const float* __restrict__ ut,
                                                 const float* __restrict__ vt,
                                                 float* __restrict__ RT) {
  __shared__ float As[16][128];
  __shared__ float Bs[16][128];
  int t = threadIdx.x;
  int d0 = blockIdx.y * 128, i0 = blockIdx.x * 128;
  int tx = t & 15, ty = t >> 4;
  float acc[8][8];
#pragma unroll
  for (int r = 0; r < 8; ++r)
#pragma unroll
    for (int c = 0; c < 8; ++c) acc[r][c] = 0.f;

  int akk = (t * 4) & 15, add0 = t >> 2;
  int eb = t * 4;
  int bkk0 = eb >> 7, bii = eb & 127, bkk1 = bkk0 + 8;
  float4 u4 = *(const float4*)&ut[i0 + bii];

  for (int k0 = 0; k0 < S; k0 += 16) {
    float4 av0 = *(const float4*)&TF[(d0 + add0) * S + k0 + akk];
    float4 av1 = *(const float4*)&TF[(d0 + add0 + 64) * S + k0 + akk];
    float4 g0 = *(const float4*)&GpT[(k0 + bkk0) * S + i0 + bii];
    float4 g1 = *(const float4*)&GpT[(k0 + bkk1) * S + i0 + bii];
    float v0 = vt[k0 + bkk0], v1 = vt[k0 + bkk1];
    __syncthreads();
    As[akk + 0][add0] = av0.x; As[akk + 1][add0] = av0.y;
    As[akk + 2][add0] = av0.z; As[akk + 3][add0] = av0.w;
    As[akk + 0][add0 + 64] = av1.x; As[akk + 1][add0 + 64] = av1.y;
    As[akk + 2][add0 + 64] = av1.z; As[akk + 3][add0 + 64] = av1.w;
    float4 p0 = make_float4(__expf(g0.x + u4.x + v0), __expf(g0.y + u4.y + v0),
                            __expf(g0.z + u4.z + v0), __expf(g0.w + u4.w + v0));
    float4 p1 = make_float4(__expf(g1.x + u4.x + v1), __expf(g1.y + u4.y + v1),
                            __expf(g1.z + u4.z + v1), __expf(g1.w + u4.w + v1));
    *(float4*)&Bs[bkk0][bii] = p0;
    *(float4*)&Bs[bkk1][bii] = p1;
    __syncthreads();
#pragma unroll
    for (int kk = 0; kk < 16; ++kk) {
      float a[8], b[8];
      *(float4*)&a[0] = *(const float4*)&As[kk][ty * 8];
      *(float4*)&a[4] = *(const float4*)&As[kk][ty * 8 + 4];
      *(float4*)&b[0] = *(const float4*)&Bs[kk][tx * 4];
      *(float4*)&b[4] = *(const float4*)&Bs[kk][64 + tx * 4];
#pragma unroll
      for (int r = 0; r < 8; ++r)
#pragma unroll
        for (int c = 0; c < 8; ++c) acc[r][c] = fmaf(a[r], b[c], acc[r][c]);
    }
  }
#pragma unroll
  for (int r = 0; r < 8; ++r) {
    int d = d0 + ty * 8 + r;
    *(float4*)&RT[d * S + i0 + tx * 4] = *(float4*)&acc[r][0];
    *(float4*)&RT[d * S + i0 + 64 + tx * 4] = *(float4*)&acc[r][4];
  }
}

// dist2[i] += sum_{d in chunk} (qa[i]*QF[d,i] - RT[d,i])^2
__global__ __launch_bounds__(256) void dist2_partial_k(const float* __restrict__ QF,
                                                       const float* __restrict__ RT,
                                                       const float* __restrict__ qa,
                                                       float* __restrict__ dist2) {
  int ib = blockIdx.x & 7, dc = blockIdx.x >> 3;
  int i = ib * 256 + threadIdx.x;
  float qai = qa[i];
  float acc = 0.f;
  int d0 = dc * 256;
  for (int d = d0; d < d0 + 256; ++d) {
    float q = QF[d * S + i];
    float r = RT[d * S + i];
    float x = fmaf(qai, q, -r);
    acc = fmaf(x, x, acc);
  }
  atomicAdd(&dist2[i], acc);
}

__global__ __launch_bounds__(256) void loss_final_k(const float* __restrict__ dist2,
                                                    const float* __restrict__ label,
                                                    float* __restrict__ out) {
  int t = threadIdx.x;
  float acc = 0.f;
#pragma unroll
  for (int k = 0; k < 8; ++k) {
    int i = t + k * 256;
    float d2 = dist2[i];
    float dist = sqrtf(d2);
    float lab = label[i];
    float neg = fmaxf(MARGIN - dist, 0.f);
    acc += 0.5f * lab * d2 + 0.5f * (1.f - lab) * neg * neg;
  }
#pragma unroll
  for (int off = 32; off; off >>= 1) acc += __shfl_xor(acc, off);
  __shared__ float wsum[4];
  int wave = t >> 6, lane = t & 63;
  if (lane == 0) wsum[wave] = acc;
  __syncthreads();
  if (t == 0) out[0] = wsum[0] + wsum[1] + wsum[2] + wsum[3];
}

// ---------------------------------------------------------------------------
extern "C" void kernel_launch(void* const* d_in, const int* in_sizes, int n_in,
                              void* d_out, int out_size, void* d_ws, size_t ws_size,
                              hipStream_t stream) {
  const float* QF  = (const float*)d_in[0];  // [D, m] d-major
  const float* qa  = (const float*)d_in[1];  // [m]
  const float* TF  = (const float*)d_in[2];  // [D, n] d-major
  const float* ta  = (const float*)d_in[3];  // [n]
  const float* lab = (const float*)d_in[4];  // [m]
  float* out = (float*)d_out;

  float* ws = (float*)d_ws;
  float* Gp    = ws;                  // S*S : G' = -2 X^T Y  (reused as RT later)
  float* GpT   = Gp + S * S;          // S*S : G'^T
  float* ut    = GpT + S * S;         // S
  float* vt    = ut + S;              // S
  float* lmu   = vt + S;              // S
  float* lnu   = lmu + S;             // S
  float* dist2 = lnu + S;             // S
  float* valU  = dist2 + S;           // [2][S] : u potential values
  float* valV  = valU + 2 * S;        // [2][S] : v potential values
  unsigned* flagU = (unsigned*)(valV + 2 * S);  // [2][256] tagged flags
  unsigned* flagV = flagU + 512;                // [2][256]
  // total: 2*S*S + 9*S floats + 1024 u32 ~= 33.6 MB

  init_marg_k<<<8, 256, 0, stream>>>(qa, ta, lmu, lnu, vt, dist2, flagU, flagV);
  colsumsq_k<<<64, 256, 0, stream>>>(TF, vt);   // vt = y2 (== v0 + y2)
  pack_v0_k<<<8, 256, 0, stream>>>(vt, valV, flagV);
  gemm_tn_k<<<dim3(16, 16), 256, 0, stream>>>(QF, TF, Gp, -2.0f);
  transpose_k<<<dim3(32, 32), 256, 0, stream>>>(Gp, GpT);

  // whole Sinkhorn loop in one persistent cooperative kernel (static 144KB LDS)
  {
    const float* cGp = Gp; const float* cGpT = GpT;
    const float* clmu = lmu; const float* clnu = lnu;
    float* cut = ut; float* cvt = vt;
    float* cvalU = valU; float* cvalV = valV;
    unsigned* cflagU = flagU; unsigned* cflagV = flagV;
    void* kargs[] = {&cGp, &cGpT, &clmu, &clnu, &cut, &cvt,
                     &cvalU, &cvalV, &cflagU, &cflagV};
    hipLaunchCooperativeKernel((const void*)sinkhorn_k, dim3(NBLK), dim3(TPB),
                               kargs, 0, stream);
  }

  // RT = P @ tf computed transposed: RT[d,i]; aliases Gp (G' dead after loop)
  rt_gemm_k<<<dim3(16, 16), 256, 0, stream>>>(TF, GpT, ut, vt, Gp);
  dist2_partial_k<<<64, 256, 0, stream>>>(QF, Gp, qa, dist2);
  loss_final_k<<<1, 256, 0, stream>>>(dist2, lab, out);
}

// Round 6
// 4735.587 us; speedup vs baseline: 1.6093x; 1.2142x over previous
//
#include <hip/hip_runtime.h>
#include <math.h>

#define S 2048
#define MARGIN 0.7f
#define ITERS 500
#define NBLK 256    // cooperative grid: 1 block/CU on 256 CUs
#define TPB 512     // 8 waves/block, wave-per-row, 8 rows/block

typedef unsigned long long u64;

// ---------------------------------------------------------------------------
// init: log-marginals, zero accumulators, poison all tags (replay-safe)
// ---------------------------------------------------------------------------
__global__ __launch_bounds__(256) void init_marg_k(const float* __restrict__ qa,
                                                   const float* __restrict__ ta,
                                                   float* __restrict__ lmu,
                                                   float* __restrict__ lnu,
                                                   float* __restrict__ vt,
                                                   float* __restrict__ dist2,
                                                   u64* __restrict__ valU,
                                                   u64* __restrict__ valV,
                                                   unsigned* __restrict__ gfu,
                                                   unsigned* __restrict__ gfv) {
  int i = blockIdx.x * 256 + threadIdx.x;   // 0..2047
  lmu[i] = __logf(qa[i]);
  lnu[i] = __logf(ta[i]);
  vt[i] = 0.f;     // will accumulate y2 (vt init = v0 + y2 = y2 since v0 = 0)
  dist2[i] = 0.f;
  const u64 poison = 0xFFFFFFFF00000000ull;  // tag never equals 0..1001
  valU[i] = poison; valU[2048 + i] = poison;
  valV[i] = poison; valV[2048 + i] = poison;
#pragma unroll
  for (int k = 0; k < 4; ++k) {              // 2048*4 = 8192 u32 each
    gfu[i * 4 + k] = 0xFFFFFFFFu;
    gfv[i * 4 + k] = 0xFFFFFFFFu;
  }
}

// vt[j] += sum_d TF[d,j]^2   (8 j-blocks x 8 d-chunks, atomic combine)
__global__ __launch_bounds__(256) void colsumsq_k(const float* __restrict__ TF,
                                                  float* __restrict__ vt) {
  int jb = blockIdx.x & 7, dc = blockIdx.x >> 3;
  int j = jb * 256 + threadIdx.x;
  int d0 = dc * 256;
  float acc = 0.f;
  for (int d = d0; d < d0 + 256; ++d) {
    float v = TF[d * S + j];
    acc = fmaf(v, v, acc);
  }
  atomicAdd(&vt[j], acc);
}

// valV slot0 <- pack(v0=y2, tag 0); gfv slot0 <- tag 0 (all 256 replicas)
__global__ __launch_bounds__(256) void pack_v0_k(const float* __restrict__ vt,
                                                 u64* __restrict__ valV,
                                                 unsigned* __restrict__ gfv) {
  int i = blockIdx.x * 256 + threadIdx.x;
  valV[i] = (u64)__float_as_uint(vt[i]);   // tag 0 in high word
  if (i < 256) gfv[i * 16] = 0u;           // slot0 entries (64B stride)
}

// ---------------------------------------------------------------------------
// C[i,j] = alpha * sum_k A[k*S+i] * B[k*S+j]   (128x128 tile, BK=16, 8x8/thread)
// ---------------------------------------------------------------------------
__global__ __launch_bounds__(256) void gemm_tn_k(const float* __restrict__ A,
                                                 const float* __restrict__ B,
                                                 float* __restrict__ C, float alpha) {
  __shared__ float As[16][128];
  __shared__ float Bs[16][128];
  int t = threadIdx.x;
  int i0 = blockIdx.y * 128, j0 = blockIdx.x * 128;
  int tx = t & 15, ty = t >> 4;
  float acc[8][8];
#pragma unroll
  for (int r = 0; r < 8; ++r)
#pragma unroll
    for (int c = 0; c < 8; ++c) acc[r][c] = 0.f;

  int e = t * 4;
  int dd0 = e >> 7, ii = e & 127;
  int dd1 = dd0 + 8;
  for (int k0 = 0; k0 < S; k0 += 16) {
    float4 a0 = *(const float4*)&A[(k0 + dd0) * S + i0 + ii];
    float4 b0 = *(const float4*)&B[(k0 + dd0) * S + j0 + ii];
    float4 a1 = *(const float4*)&A[(k0 + dd1) * S + i0 + ii];
    float4 b1 = *(const float4*)&B[(k0 + dd1) * S + j0 + ii];
    __syncthreads();
    *(float4*)&As[dd0][ii] = a0; *(float4*)&Bs[dd0][ii] = b0;
    *(float4*)&As[dd1][ii] = a1; *(float4*)&Bs[dd1][ii] = b1;
    __syncthreads();
#pragma unroll
    for (int kk = 0; kk < 16; ++kk) {
      float a[8], b[8];
      *(float4*)&a[0] = *(const float4*)&As[kk][ty * 8];
      *(float4*)&a[4] = *(const float4*)&As[kk][ty * 8 + 4];
      *(float4*)&b[0] = *(const float4*)&Bs[kk][tx * 4];
      *(float4*)&b[4] = *(const float4*)&Bs[kk][64 + tx * 4];
#pragma unroll
      for (int r = 0; r < 8; ++r)
#pragma unroll
        for (int c = 0; c < 8; ++c) acc[r][c] = fmaf(a[r], b[c], acc[r][c]);
    }
  }
#pragma unroll
  for (int r = 0; r < 8; ++r) {
    int i = i0 + ty * 8 + r;
    float4 o0 = make_float4(acc[r][0] * alpha, acc[r][1] * alpha, acc[r][2] * alpha, acc[r][3] * alpha);
    float4 o1 = make_float4(acc[r][4] * alpha, acc[r][5] * alpha, acc[r][6] * alpha, acc[r][7] * alpha);
    *(float4*)&C[i * S + j0 + tx * 4] = o0;
    *(float4*)&C[i * S + j0 + 64 + tx * 4] = o1;
  }
}

// ---------------------------------------------------------------------------
// out[j*S+i] = in[i*S+j]  (64x64 LDS tiles)
// ---------------------------------------------------------------------------
__global__ __launch_bounds__(256) void transpose_k(const float* __restrict__ in,
                                                   float* __restrict__ out) {
  __shared__ float tile[64][65];
  int i0 = blockIdx.y * 64, j0 = blockIdx.x * 64;
  int tx = threadIdx.x & 63, ty = threadIdx.x >> 6;  // ty 0..3
#pragma unroll
  for (int r = 0; r < 16; ++r) {
    int row = r * 4 + ty;
    tile[row][tx] = in[(i0 + row) * S + j0 + tx];
  }
  __syncthreads();
#pragma unroll
  for (int r = 0; r < 16; ++r) {
    int row = r * 4 + ty;
    out[(j0 + row) * S + i0 + tx] = tile[tx][row];
  }
}

// ---------------------------------------------------------------------------
// Persistent cooperative Sinkhorn — LDS-resident G + aggregation-tree dataflow.
//
// Lesson from rounds 3/4/5 (4.47/6.8/4.98 us/phase, all ~1.2us theoretical):
// the dominating term is POLL-LOAD CONTENTION at the LLC coherence point —
// phase time inflates until poll rate matches per-line service rate. This
// version caps per-line poll pressure everywhere:
//   producer: 8 lane0s store (tag<<32|value) u64s into the block's PRIVATE
//             64B line (payload+flag in one atomic word; no drain, no flag).
//   16 aggregators: poll own group's 16 lines (8 loads/round/line), then
//             store a group-ready tag replicated x16 (one line per cohort).
//   consumer: polls 16 group-flag lines, each shared by only 16 blocks
//             (~0.04 loads/cyc/line), then bulk-reads the 2048 values ONCE
//             (no polling) and deposits as conflict-free float4s to LDS.
// Tags strictly increase; poisoned in init (graph-replay safe). WAR on the
// double-buffered slots: overwrite at phase p+2 requires all blocks past
// consuming phase p (same 2-phase-lag argument as rounds 3-5). Deadlock-
// free: every block publishes before it blocks. Arithmetic bit-identical
// to the verified rounds (absmax 0.0).
// ---------------------------------------------------------------------------
#define PADD(P, A) P.x += A.x; P.y += A.y; P.z += A.z; P.w += A.w
#define PMAX(P) fmaxf(fmaxf(P.x, P.y), fmaxf(P.z, P.w))
#define PEXPS(P) (__expf(P.x - m) + __expf(P.y - m) + __expf(P.z - m) + __expf(P.w - m))

// aggregator duty (bid%16==0): wave0 polls the group's 16 value-lines (all
// 8 tags each), then lanes 0..15 store the group-ready tag to 16 cohort lines
__device__ __forceinline__ void aggregate(const u64* __restrict__ val,
                                          unsigned* __restrict__ gf,
                                          int slot, unsigned tag,
                                          int t, int group) {
  if (t < 64) {
    const u64* base = val + ((size_t)slot << 11)
                      + (((group << 4) + (t >> 2)) << 3) + ((t & 3) << 1);
    unsigned got = 0;
    while (!__all(got == 3u)) {
      if (!(got & 1u) &&
          (unsigned)(__hip_atomic_load(&base[0], __ATOMIC_RELAXED,
                                       __HIP_MEMORY_SCOPE_AGENT) >> 32) == tag)
        got |= 1u;
      if (!(got & 2u) &&
          (unsigned)(__hip_atomic_load(&base[1], __ATOMIC_RELAXED,
                                       __HIP_MEMORY_SCOPE_AGENT) >> 32) == tag)
        got |= 2u;
    }
    if (t < 16) {
      unsigned* g = gf + ((size_t)slot << 12) + (size_t)(((group << 4) + t) << 4);
      __hip_atomic_store(g, tag, __ATOMIC_RELAXED, __HIP_MEMORY_SCOPE_AGENT);
    }
  }
}

// consumer: wave0 lanes 0..15 poll the 16 group flags (cohort replica), then
// all 512 threads bulk-read the 2048 tagged values once -> float4 -> LDS
__device__ __forceinline__ void consume_pot(const u64* __restrict__ val,
                                            const unsigned* __restrict__ gf,
                                            int slot, unsigned tag,
                                            float* __restrict__ s_pot,
                                            int t, int cohort) {
  if (t < 64) {
    unsigned ok = (t < 16) ? 0u : 1u;
    const unsigned* gbase = gf + ((size_t)slot << 12);
    const int idx = ((t << 4) + cohort) << 4;   // (group=t)*16+cohort, 64B stride
    while (!__all(ok != 0u)) {
      if (t < 16 && !ok) {
        if (__hip_atomic_load(&gbase[idx], __ATOMIC_RELAXED,
                              __HIP_MEMORY_SCOPE_AGENT) == tag)
          ok = 1u;
      }
    }
  }
  __syncthreads();
  const u64* src = val + ((size_t)slot << 11);
  int e = t << 2;
  u64 w0 = __hip_atomic_load(&src[e + 0], __ATOMIC_RELAXED, __HIP_MEMORY_SCOPE_AGENT);
  u64 w1 = __hip_atomic_load(&src[e + 1], __ATOMIC_RELAXED, __HIP_MEMORY_SCOPE_AGENT);
  u64 w2 = __hip_atomic_load(&src[e + 2], __ATOMIC_RELAXED, __HIP_MEMORY_SCOPE_AGENT);
  u64 w3 = __hip_atomic_load(&src[e + 3], __ATOMIC_RELAXED, __HIP_MEMORY_SCOPE_AGENT);
  float4 f = make_float4(__uint_as_float((unsigned)w0),
                         __uint_as_float((unsigned)w1),
                         __uint_as_float((unsigned)w2),
                         __uint_as_float((unsigned)w3));
  *(float4*)&s_pot[e] = f;
  __syncthreads();
}

// wave-uniform LSE over 2048 entries of (grow[j] + s_pot[j]); exact row max
__device__ __forceinline__ float lse_row(const float* __restrict__ grow,
                                         const float* __restrict__ s_pot,
                                         int lane) {
  int j0 = lane << 2;
  float4 p0 = *(const float4*)&s_pot[j0];
  float4 p1 = *(const float4*)&s_pot[j0 + 256];
  float4 p2 = *(const float4*)&s_pot[j0 + 512];
  float4 p3 = *(const float4*)&s_pot[j0 + 768];
  float4 p4 = *(const float4*)&s_pot[j0 + 1024];
  float4 p5 = *(const float4*)&s_pot[j0 + 1280];
  float4 p6 = *(const float4*)&s_pot[j0 + 1536];
  float4 p7 = *(const float4*)&s_pot[j0 + 1792];
  float4 a0 = *(const float4*)&grow[j0];
  float4 a1 = *(const float4*)&grow[j0 + 256];
  float4 a2 = *(const float4*)&grow[j0 + 512];
  float4 a3 = *(const float4*)&grow[j0 + 768];
  float4 a4 = *(const float4*)&grow[j0 + 1024];
  float4 a5 = *(const float4*)&grow[j0 + 1280];
  float4 a6 = *(const float4*)&grow[j0 + 1536];
  float4 a7 = *(const float4*)&grow[j0 + 1792];
  PADD(p0, a0); PADD(p1, a1); PADD(p2, a2); PADD(p3, a3);
  PADD(p4, a4); PADD(p5, a5); PADD(p6, a6); PADD(p7, a7);
  float m0 = PMAX(p0), m1 = PMAX(p1), m2 = PMAX(p2), m3 = PMAX(p3);
  float m4 = PMAX(p4), m5 = PMAX(p5), m6 = PMAX(p6), m7 = PMAX(p7);
  m0 = fmaxf(m0, m1); m2 = fmaxf(m2, m3); m4 = fmaxf(m4, m5); m6 = fmaxf(m6, m7);
  float m = fmaxf(fmaxf(m0, m2), fmaxf(m4, m6));
#pragma unroll
  for (int off = 32; off; off >>= 1) m = fmaxf(m, __shfl_xor(m, off));
  float s = PEXPS(p0) + PEXPS(p1) + PEXPS(p2) + PEXPS(p3) +
            PEXPS(p4) + PEXPS(p5) + PEXPS(p6) + PEXPS(p7);
#pragma unroll
  for (int off = 32; off; off >>= 1) s += __shfl_xor(s, off);
  return m + __logf(s);
}

__global__ __launch_bounds__(TPB) void sinkhorn_k(
    const float* __restrict__ Gp, const float* __restrict__ GpT,
    const float* __restrict__ lmu, const float* __restrict__ lnu,
    float* __restrict__ ut, float* __restrict__ vt,
    u64* __restrict__ valU, u64* __restrict__ valV,
    unsigned* __restrict__ gfu, unsigned* __restrict__ gfv) {
  __shared__ float s_gu[8 * S];    // 64KB: this block's 8 Gp rows
  __shared__ float s_gv[8 * S];    // 64KB: this block's 8 GpT rows
  __shared__ float s_potA[S];      // 8KB : staged v for u-pass
  __shared__ float s_potB[S];      // 8KB : staged u for v-pass

  const int t = threadIdx.x;
  const int wv = t >> 6, lane = t & 63;
  const int bid = (int)blockIdx.x;
  const int row = (bid << 3) + wv;
  const int cohort = bid & 15;
  const int group = bid >> 4;
  const bool isAgg = (cohort == 0);

  // one-time stage of this block's G rows into LDS
  {
    const float* gu = Gp + (size_t)row * S;
    const float* gv = GpT + (size_t)row * S;
    float* lgu = s_gu + wv * S;
    float* lgv = s_gv + wv * S;
#pragma unroll
    for (int c = 0; c < 8; ++c) {
      int j = (lane << 2) + (c << 8);
      *(float4*)&lgu[j] = *(const float4*)&gu[j];
      *(float4*)&lgv[j] = *(const float4*)&gv[j];
    }
  }
  const float lmu_r = lmu[row];
  const float lnu_r = lnu[row];
  const float* grow_u = s_gu + wv * S;
  const float* grow_v = s_gv + wv * S;
  float uLast = 0.f, vLast = 0.f;
  __syncthreads();

  for (int it = 0; it < ITERS; ++it) {
    const int s = it & 1;
    const unsigned vt_tag = 2u * (unsigned)it;   // v_t
    const unsigned ut_tag = vt_tag + 1u;         // u_t

    // ---- u-pass: u_t[row] = lmu - LSE_j(Gp[row,j] + v_t[j]) ----
    consume_pot(valV, gfv, s, vt_tag, s_potA, t, cohort);
    {
      float nu = lmu_r - lse_row(grow_u, s_potA, lane);
      uLast = nu;
      if (lane == 0)
        __hip_atomic_store(&valU[((size_t)s << 11) + (bid << 3) + wv],
                           ((u64)ut_tag << 32) | (u64)__float_as_uint(nu),
                           __ATOMIC_RELAXED, __HIP_MEMORY_SCOPE_AGENT);
    }
    if (isAgg) aggregate(valU, gfu, s, ut_tag, t, group);

    // ---- v-pass: v_{t+1}[row] = lnu - LSE_i(GpT[row,i] + u_t[i]) ----
    consume_pot(valU, gfu, s, ut_tag, s_potB, t, cohort);
    {
      float nv = lnu_r - lse_row(grow_v, s_potB, lane);
      vLast = nv;
      const int s2 = s ^ 1;
      if (lane == 0)
        __hip_atomic_store(&valV[((size_t)s2 << 11) + (bid << 3) + wv],
                           ((u64)(vt_tag + 2u) << 32) | (u64)__float_as_uint(nv),
                           __ATOMIC_RELAXED, __HIP_MEMORY_SCOPE_AGENT);
      if (isAgg) aggregate(valV, gfv, s2, vt_tag + 2u, t, group);
    }
  }
  // final potentials -> plain arrays for the epilogue kernels
  // (end-of-kernel release handles cross-kernel visibility)
  if (lane == 0) {
    ut[row] = uLast;
    vt[row] = vLast;
  }
}

// ---------------------------------------------------------------------------
// RT[d,i] = sum_j TF[d,j] * exp( GpT[j*S+i] + ut[i] + vt[j] )
// ---------------------------------------------------------------------------
__global__ __launch_bounds__(256) void rt_gemm_k(const float* __restrict__ TF,
                                                 const float* __restrict__ GpT,
                                                 const float* __restrict__ ut,
                                                 const float* __restrict__ vt,
                                                 float* __restrict__ RT) {
  __shared__ float As[16][128];
  __shared__ float Bs[16][128];
  int t = threadIdx.x;
  int d0 = blockIdx.y * 128, i0 = blockIdx.x * 128;
  int tx = t & 15, ty = t >> 4;
  float acc[8][8];
#pragma unroll
  for (int r = 0; r < 8; ++r)
#pragma unroll
    for (int c = 0; c < 8; ++c) acc[r][c] = 0.f;

  int akk = (t * 4) & 15, add0 = t >> 2;
  int eb = t * 4;
  int bkk0 = eb >> 7, bii = eb & 127, bkk1 = bkk0 + 8;
  float4 u4 = *(const float4*)&ut[i0 + bii];

  for (int k0 = 0; k0 < S; k0 += 16) {
    float4 av0 = *(const float4*)&TF[(d0 + add0) * S + k0 + akk];
    float4 av1 = *(const float4*)&TF[(d0 + add0 + 64) * S + k0 + akk];
    float4 g0 = *(const float4*)&GpT[(k0 + bkk0) * S + i0 + bii];
    float4 g1 = *(const float4*)&GpT[(k0 + bkk1) * S + i0 + bii];
    float v0 = vt[k0 + bkk0], v1 = vt[k0 + bkk1];
    __syncthreads();
    As[akk + 0][add0] = av0.x; As[akk + 1][add0] = av0.y;
    As[akk + 2][add0] = av0.z; As[akk + 3][add0] = av0.w;
    As[akk + 0][add0 + 64] = av1.x; As[akk + 1][add0 + 64] = av1.y;
    As[akk + 2][add0 + 64] = av1.z; As[akk + 3][add0 + 64] = av1.w;
    float4 p0 = make_float4(__expf(g0.x + u4.x + v0), __expf(g0.y + u4.y + v0),
                            __expf(g0.z + u4.z + v0), __expf(g0.w + u4.w + v0));
    float4 p1 = make_float4(__expf(g1.x + u4.x + v1), __expf(g1.y + u4.y + v1),
                            __expf(g1.z + u4.z + v1), __expf(g1.w + u4.w + v1));
    *(float4*)&Bs[bkk0][bii] = p0;
    *(float4*)&Bs[bkk1][bii] = p1;
    __syncthreads();
#pragma unroll
    for (int kk = 0; kk < 16; ++kk) {
      float a[8], b[8];
      *(float4*)&a[0] = *(const float4*)&As[kk][ty * 8];
      *(float4*)&a[4] = *(const float4*)&As[kk][ty * 8 + 4];
      *(float4*)&b[0] = *(const float4*)&Bs[kk][tx * 4];
      *(float4*)&b[4] = *(const float4*)&Bs[kk][64 + tx * 4];
#pragma unroll
      for (int r = 0; r < 8; ++r)
#pragma unroll
        for (int c = 0; c < 8; ++c) acc[r][c] = fmaf(a[r], b[c], acc[r][c]);
    }
  }
#pragma unroll
  for (int r = 0; r < 8; ++r) {
    int d = d0 + ty * 8 + r;
    *(float4*)&RT[d * S + i0 + tx * 4] = *(float4*)&acc[r][0];
    *(float4*)&RT[d * S + i0 + 64 + tx * 4] = *(float4*)&acc[r][4];
  }
}

// dist2[i] += sum_{d in chunk} (qa[i]*QF[d,i] - RT[d,i])^2
__global__ __launch_bounds__(256) void dist2_partial_k(const float* __restrict__ QF,
                                                       const float* __restrict__ RT,
                                                       const float* __restrict__ qa,
                                                       float* __restrict__ dist2) {
  int ib = blockIdx.x & 7, dc = blockIdx.x >> 3;
  int i = ib * 256 + threadIdx.x;
  float qai = qa[i];
  float acc = 0.f;
  int d0 = dc * 256;
  for (int d = d0; d < d0 + 256; ++d) {
    float q = QF[d * S + i];
    float r = RT[d * S + i];
    float x = fmaf(qai, q, -r);
    acc = fmaf(x, x, acc);
  }
  atomicAdd(&dist2[i], acc);
}

__global__ __launch_bounds__(256) void loss_final_k(const float* __restrict__ dist2,
                                                    const float* __restrict__ label,
                                                    float* __restrict__ out) {
  int t = threadIdx.x;
  float acc = 0.f;
#pragma unroll
  for (int k = 0; k < 8; ++k) {
    int i = t + k * 256;
    float d2 = dist2[i];
    float dist = sqrtf(d2);
    float lab = label[i];
    float neg = fmaxf(MARGIN - dist, 0.f);
    acc += 0.5f * lab * d2 + 0.5f * (1.f - lab) * neg * neg;
  }
#pragma unroll
  for (int off = 32; off; off >>= 1) acc += __shfl_xor(acc, off);
  __shared__ float wsum[4];
  int wave = t >> 6, lane = t & 63;
  if (lane == 0) wsum[wave] = acc;
  __syncthreads();
  if (t == 0) out[0] = wsum[0] + wsum[1] + wsum[2] + wsum[3];
}

// ---------------------------------------------------------------------------
extern "C" void kernel_launch(void* const* d_in, const int* in_sizes, int n_in,
                              void* d_out, int out_size, void* d_ws, size_t ws_size,
                              hipStream_t stream) {
  const float* QF  = (const float*)d_in[0];  // [D, m] d-major
  const float* qa  = (const float*)d_in[1];  // [m]
  const float* TF  = (const float*)d_in[2];  // [D, n] d-major
  const float* ta  = (const float*)d_in[3];  // [n]
  const float* lab = (const float*)d_in[4];  // [m]
  float* out = (float*)d_out;

  float* ws = (float*)d_ws;
  float* Gp    = ws;                  // S*S : G' = -2 X^T Y  (reused as RT later)
  float* GpT   = Gp + S * S;          // S*S : G'^T
  float* ut    = GpT + S * S;         // S
  float* vt    = ut + S;              // S
  float* lmu   = vt + S;              // S
  float* lnu   = lmu + S;             // S
  float* dist2 = lnu + S;             // S
  u64* valU = (u64*)(dist2 + S);      // [2][2048] tagged u values (32KB)
  u64* valV = valU + 2 * S;           // [2][2048] tagged v values (32KB)
  unsigned* gfu = (unsigned*)(valV + 2 * S);  // [2][256] x 16-u32 pad (32KB)
  unsigned* gfv = gfu + 8192;                 // [2][256] x 16-u32 pad (32KB)
  // total: 2*S*S + 5*S floats + 128KB sync state ~= 33.7 MB

  init_marg_k<<<8, 256, 0, stream>>>(qa, ta, lmu, lnu, vt, dist2,
                                     valU, valV, gfu, gfv);
  colsumsq_k<<<64, 256, 0, stream>>>(TF, vt);   // vt = y2 (== v0 + y2)
  pack_v0_k<<<8, 256, 0, stream>>>(vt, valV, gfv);
  gemm_tn_k<<<dim3(16, 16), 256, 0, stream>>>(QF, TF, Gp, -2.0f);
  transpose_k<<<dim3(32, 32), 256, 0, stream>>>(Gp, GpT);

  // whole Sinkhorn loop in one persistent cooperative kernel (static 144KB LDS)
  {
    const float* cGp = Gp; const float* cGpT = GpT;
    const float* clmu = lmu; const float* clnu = lnu;
    float* cut = ut; float* cvt = vt;
    u64* cvalU = valU; u64* cvalV = valV;
    unsigned* cgfu = gfu; unsigned* cgfv = gfv;
    void* kargs[] = {&cGp, &cGpT, &clmu, &clnu, &cut, &cvt,
                     &cvalU, &cvalV, &cgfu, &cgfv};
    hipLaunchCooperativeKernel((const void*)sinkhorn_k, dim3(NBLK), dim3(TPB),
                               kargs, 0, stream);
  }

  // RT = P @ tf computed transposed: RT[d,i]; aliases Gp (G' dead after loop)
  rt_gemm_k<<<dim3(16, 16), 256, 0, stream>>>(TF, GpT, ut, vt, Gp);
  dist2_partial_k<<<64, 256, 0, stream>>>(QF, Gp, qa, dist2);
  loss_final_k<<<1, 256, 0, stream>>>(dist2, lab, out);
}